// Round 1
// baseline (103.311 us; speedup 1.0000x reference)
//
#include <hip/hip_runtime.h>
#include <math.h>

// Exact erf-based GELU, fp32 -> fp32, memory-bound elementwise.
// n = 4*4096*4096 = 67,108,864 elements; vectorized as float4 (16 B/lane).

__global__ void __launch_bounds__(256) gelu_f32_kernel(
    const float4* __restrict__ x, float4* __restrict__ out, int n4) {
    const float kInvSqrt2 = 0.70710678118654752440f;
    int idx = blockIdx.x * blockDim.x + threadIdx.x;
    int stride = gridDim.x * blockDim.x;
    for (int i = idx; i < n4; i += stride) {
        float4 v = x[i];
        float4 r;
        r.x = 0.5f * v.x * (1.0f + erff(v.x * kInvSqrt2));
        r.y = 0.5f * v.y * (1.0f + erff(v.y * kInvSqrt2));
        r.z = 0.5f * v.z * (1.0f + erff(v.z * kInvSqrt2));
        r.w = 0.5f * v.w * (1.0f + erff(v.w * kInvSqrt2));
        out[i] = r;
    }
}

// Scalar tail kernel (defensive; n is divisible by 4 for this problem).
__global__ void gelu_f32_tail_kernel(
    const float* __restrict__ x, float* __restrict__ out, int start, int n) {
    const float kInvSqrt2 = 0.70710678118654752440f;
    int i = start + blockIdx.x * blockDim.x + threadIdx.x;
    if (i < n) {
        float v = x[i];
        out[i] = 0.5f * v * (1.0f + erff(v * kInvSqrt2));
    }
}

extern "C" void kernel_launch(void* const* d_in, const int* in_sizes, int n_in,
                              void* d_out, int out_size, void* d_ws, size_t ws_size,
                              hipStream_t stream) {
    const float* x = (const float*)d_in[0];
    float* out = (float*)d_out;
    int n = in_sizes[0];
    int n4 = n / 4;

    const int block = 256;
    int grid = (n4 + block - 1) / block;
    if (grid > 2048) grid = 2048;  // grid-stride beyond this
    if (grid > 0) {
        gelu_f32_kernel<<<grid, block, 0, stream>>>(
            (const float4*)x, (float4*)out, n4);
    }

    int tail_start = n4 * 4;
    int tail = n - tail_start;
    if (tail > 0) {
        gelu_f32_tail_kernel<<<1, 64, 0, stream>>>(x, out, tail_start, n);
    }
}

// Round 3
// 100.069 us; speedup vs baseline: 1.0324x; 1.0324x over previous
//
#include <hip/hip_runtime.h>
#include <math.h>

// Exact-enough GELU (tanh form, max dev ~3e-4 from erf form; threshold 0.104),
// fp32 -> fp32, memory-bound elementwise. n = 4*4096*4096 = 67,108,864.
// gelu(x) = 0.5*x*(1+tanh(c0*(x+c1*x^3))) rewritten as x*u/(u+1),
// u = exp2(x*(A + B*x^2)), A = 2*log2(e)*c0, B = A*c1.

typedef float f32x4 __attribute__((ext_vector_type(4)));

__device__ __forceinline__ float gelu_fast(float v) {
    const float A = 2.30220771796f;    // 2*log2(e)*sqrt(2/pi)
    const float B = 0.102943213f;      // A * 0.044715
    float x2 = v * v;
    float p = fmaf(x2, B, A);
    float arg = v * p;
    // clamp defensively against exp2 overflow -> inf*rcp -> NaN
    arg = fminf(fmaxf(arg, -126.0f), 126.0f);
    float u = __builtin_amdgcn_exp2f(arg);
    float r = __builtin_amdgcn_rcpf(u + 1.0f);
    return v * u * r;
}

__global__ void __launch_bounds__(256) gelu_f32_kernel(
    const f32x4* __restrict__ x, f32x4* __restrict__ out, int n4) {
    int idx = blockIdx.x * blockDim.x + threadIdx.x;
    int stride = gridDim.x * blockDim.x;
    for (int i = idx; i < n4; i += stride) {
        f32x4 v = __builtin_nontemporal_load(&x[i]);
        f32x4 r;
        r.x = gelu_fast(v.x);
        r.y = gelu_fast(v.y);
        r.z = gelu_fast(v.z);
        r.w = gelu_fast(v.w);
        __builtin_nontemporal_store(r, &out[i]);
    }
}

// Scalar tail kernel (defensive; n is divisible by 4 for this problem).
__global__ void gelu_f32_tail_kernel(
    const float* __restrict__ x, float* __restrict__ out, int start, int n) {
    int i = start + blockIdx.x * blockDim.x + threadIdx.x;
    if (i < n) {
        out[i] = gelu_fast(x[i]);
    }
}

extern "C" void kernel_launch(void* const* d_in, const int* in_sizes, int n_in,
                              void* d_out, int out_size, void* d_ws, size_t ws_size,
                              hipStream_t stream) {
    const float* x = (const float*)d_in[0];
    float* out = (float*)d_out;
    int n = in_sizes[0];
    int n4 = n / 4;

    const int block = 256;
    int grid = (n4 + block - 1) / block;
    if (grid > 2048) grid = 2048;  // grid-stride beyond this
    if (grid > 0) {
        gelu_f32_kernel<<<grid, block, 0, stream>>>(
            (const f32x4*)x, (f32x4*)out, n4);
    }

    int tail_start = n4 * 4;
    int tail = n - tail_start;
    if (tail > 0) {
        gelu_f32_tail_kernel<<<1, 64, 0, stream>>>(x, out, tail_start, n);
    }
}